// Round 1
// baseline (861.275 us; speedup 1.0000x reference)
//
#include <hip/hip_runtime.h>
#include <hip/hip_bf16.h>

// GCNConv: out = scatter_add(norm * (x@W+b)[col] -> row) with self loops.
// N=50000, E=1.6M, D=128, fp32.
//
// ws layout: [0, 25.6MB) xl = x@W+b ; [25.6MB, +200KB) deg->dis (in place)

#define D 128

// --- degree = 1 (self loop) ---------------------------------------------
__global__ __launch_bounds__(256) void k_init_deg(float* __restrict__ deg, int N) {
    int i = blockIdx.x * 256 + threadIdx.x;
    if (i < N) deg[i] = 1.0f;
}

// --- deg[col[e]] += 1 ----------------------------------------------------
__global__ __launch_bounds__(256) void k_count(const int* __restrict__ cols,
                                               float* __restrict__ deg, int E) {
    int e = blockIdx.x * 256 + threadIdx.x;
    if (e < E) atomicAdd(&deg[cols[e]], 1.0f);
}

// --- dis = rsqrt(deg) in place ------------------------------------------
__global__ __launch_bounds__(256) void k_dis(float* __restrict__ deg, int N) {
    int i = blockIdx.x * 256 + threadIdx.x;
    if (i < N) deg[i] = rsqrtf(deg[i]);
}

// --- xl = x @ W + b ------------------------------------------------------
// block = 128 threads (thread = output col), 8 rows per block.
// x tile staged in LDS (broadcast ds_read_b128); W streamed from L2 (64KB,
// reused by all 6250 blocks).
#define GEMM_R 8
__global__ __launch_bounds__(128) void k_gemm(const float* __restrict__ x,
                                              const float* __restrict__ W,
                                              const float* __restrict__ b,
                                              float* __restrict__ xl, int N) {
    __shared__ float xs[GEMM_R][D];
    const int c  = threadIdx.x;          // 0..127
    const int r0 = blockIdx.x * GEMM_R;
    #pragma unroll
    for (int r = 0; r < GEMM_R; ++r) {
        int row = r0 + r;
        xs[r][c] = (row < N) ? x[row * D + c] : 0.0f;
    }
    __syncthreads();

    float acc[GEMM_R];
    const float bc = b[c];
    #pragma unroll
    for (int r = 0; r < GEMM_R; ++r) acc[r] = bc;

    for (int k = 0; k < D; k += 4) {
        const float w0 = W[(k + 0) * D + c];
        const float w1 = W[(k + 1) * D + c];
        const float w2 = W[(k + 2) * D + c];
        const float w3 = W[(k + 3) * D + c];
        #pragma unroll
        for (int r = 0; r < GEMM_R; ++r) {
            const float4 xv = *reinterpret_cast<const float4*>(&xs[r][k]);
            acc[r] = fmaf(xv.x, w0, acc[r]);
            acc[r] = fmaf(xv.y, w1, acc[r]);
            acc[r] = fmaf(xv.z, w2, acc[r]);
            acc[r] = fmaf(xv.w, w3, acc[r]);
        }
    }
    #pragma unroll
    for (int r = 0; r < GEMM_R; ++r) {
        int row = r0 + r;
        if (row < N) xl[row * D + c] = acc[r];
    }
}

// --- out[i] = dis[i]^2 * xl[i]  (self-loop message, also inits out) ------
__global__ __launch_bounds__(256) void k_self(const float* __restrict__ xl,
                                              const float* __restrict__ dis,
                                              float* __restrict__ out, int N) {
    int gid = blockIdx.x * 256 + threadIdx.x;   // over N*D
    int i = gid >> 7;
    if (i < N) {
        float d = dis[i];
        out[gid] = d * d * xl[gid];
    }
}

// --- per-edge scatter: out[row] += dis[row]*dis[col] * xl[col] -----------
// one wave per edge; lane handles cols {lane, lane+64} so each atomic
// instruction touches 256B contiguous.
__global__ __launch_bounds__(256) void k_scatter(const int* __restrict__ rows,
                                                 const int* __restrict__ cols,
                                                 const float* __restrict__ dis,
                                                 const float* __restrict__ xl,
                                                 float* __restrict__ out, int E) {
    long long gid = (long long)blockIdx.x * 256 + threadIdx.x;
    int e    = (int)(gid >> 6);
    int lane = (int)(gid & 63);
    if (e >= E) return;
    const int row = rows[e];
    const int col = cols[e];
    const float nrm = dis[row] * dis[col];
    const float v0 = xl[col * D + lane];
    const float v1 = xl[col * D + 64 + lane];
    atomicAdd(&out[row * D + lane],      nrm * v0);
    atomicAdd(&out[row * D + 64 + lane], nrm * v1);
}

extern "C" void kernel_launch(void* const* d_in, const int* in_sizes, int n_in,
                              void* d_out, int out_size, void* d_ws, size_t ws_size,
                              hipStream_t stream) {
    const float* x    = (const float*)d_in[0];
    const int*   ei   = (const int*)d_in[1];   // [2, E] flat
    const float* W    = (const float*)d_in[2];
    const float* b    = (const float*)d_in[3];
    float*       out  = (float*)d_out;

    const int N = in_sizes[0] / D;             // 50000
    const int E = in_sizes[1] / 2;             // 1.6M
    const int* rows = ei;
    const int* cols = ei + E;

    float* xl  = (float*)d_ws;                         // N*D floats
    float* dis = (float*)((char*)d_ws + (size_t)N * D * sizeof(float)); // N floats

    // degree -> dis
    k_init_deg<<<(N + 255) / 256, 256, 0, stream>>>(dis, N);
    k_count  <<<(E + 255) / 256, 256, 0, stream>>>(cols, dis, E);
    k_dis    <<<(N + 255) / 256, 256, 0, stream>>>(dis, N);

    // xl = x@W + b
    k_gemm<<<(N + GEMM_R - 1) / GEMM_R, 128, 0, stream>>>(x, W, b, xl, N);

    // out = self-loop messages
    k_self<<<((long long)N * D + 255) / 256, 256, 0, stream>>>(xl, dis, out, N);

    // edge scatter
    long long scatter_threads = (long long)E * 64;
    k_scatter<<<(scatter_threads + 255) / 256, 256, 0, stream>>>(rows, cols, dis, xl, out, E);
}

// Round 2
// 473.359 us; speedup vs baseline: 1.8195x; 1.8195x over previous
//
#include <hip/hip_runtime.h>
#include <hip/hip_bf16.h>

// GCNConv: out[i] = sum_{e: row[e]=i} dis[i]*dis[col]*xl[col] + dis[i]^2*xl[i]
// N=50000, E=1.6M, D=128, fp32.
//
// R1 -> R2: replace fp32 atomic scatter (639us, 800MB HBM write-through) with
// on-device CSR build + gather-side reduction (no fp32 atomics on out).

#define D 128
#define SCAN_B 256

// ======================= CSR-build path ==================================

// zero the two int histograms (2N ints)
__global__ __launch_bounds__(256) void k_zero(int* __restrict__ p, int n) {
    int i = blockIdx.x * 256 + threadIdx.x;
    if (i < n) p[i] = 0;
}

// cntr[row[e]]++ (CSR counts), cntc[col[e]]++ (degree)
__global__ __launch_bounds__(256) void k_hist(const int* __restrict__ rows,
                                              const int* __restrict__ cols,
                                              int* __restrict__ cntr,
                                              int* __restrict__ cntc, int E) {
    int e = blockIdx.x * 256 + threadIdx.x;
    if (e < E) {
        atomicAdd(&cntr[rows[e]], 1);
        atomicAdd(&cntc[cols[e]], 1);
    }
}

// dis[i] = rsqrt(deg_col[i] + 1)   (+1 = self loop; always >= 1)
__global__ __launch_bounds__(256) void k_dis(const int* __restrict__ cntc,
                                             float* __restrict__ dis, int N) {
    int i = blockIdx.x * 256 + threadIdx.x;
    if (i < N) dis[i] = rsqrtf((float)(cntc[i] + 1));
}

// scan stage 1: per-block inclusive scan of cnt, block sums out
__global__ __launch_bounds__(SCAN_B) void k_scan1(const int* __restrict__ cnt,
                                                  int* __restrict__ incl,
                                                  int* __restrict__ bsum, int N) {
    __shared__ int s[SCAN_B];
    int t = threadIdx.x, g = blockIdx.x * SCAN_B + t;
    int v = (g < N) ? cnt[g] : 0;
    s[t] = v;
    __syncthreads();
    for (int off = 1; off < SCAN_B; off <<= 1) {
        int add = (t >= off) ? s[t - off] : 0;
        __syncthreads();
        s[t] += add;
        __syncthreads();
    }
    if (g < N) incl[g] = s[t];
    if (t == SCAN_B - 1) bsum[blockIdx.x] = s[t];
}

// scan stage 2: exclusive scan of block sums (nb <= 256), in place
__global__ __launch_bounds__(SCAN_B) void k_scan2(int* __restrict__ bsum, int nb) {
    __shared__ int s[SCAN_B];
    int t = threadIdx.x;
    int v = (t < nb) ? bsum[t] : 0;
    s[t] = v;
    __syncthreads();
    for (int off = 1; off < SCAN_B; off <<= 1) {
        int add = (t >= off) ? s[t - off] : 0;
        __syncthreads();
        s[t] += add;
        __syncthreads();
    }
    if (t < nb) bsum[t] = s[t] - v;  // exclusive
}

// scan stage 3: exclusive offsets + cursor copy; offs[N] = E
__global__ __launch_bounds__(SCAN_B) void k_scan3(const int* __restrict__ incl,
                                                  const int* __restrict__ cnt,
                                                  const int* __restrict__ bsum,
                                                  int* __restrict__ offs,
                                                  int* __restrict__ cursor,
                                                  int N, int E) {
    int g = blockIdx.x * SCAN_B + threadIdx.x;
    if (g < N) {
        int ex = incl[g] - cnt[g] + bsum[blockIdx.x];
        offs[g] = ex;
        cursor[g] = ex;
    }
    if (g == 0) offs[N] = E;
}

// bin edges into CSR order: ecol[pos] = col
__global__ __launch_bounds__(256) void k_bin(const int* __restrict__ rows,
                                             const int* __restrict__ cols,
                                             int* __restrict__ cursor,
                                             int* __restrict__ ecol, int E) {
    int e = blockIdx.x * 256 + threadIdx.x;
    if (e < E) {
        int p = atomicAdd(&cursor[rows[e]], 1);
        ecol[p] = cols[e];
    }
}

// gather-reduce: one block (128 thr) per node; self loop folded into init
__global__ __launch_bounds__(128) void k_reduce(const int* __restrict__ offs,
                                                const int* __restrict__ ecol,
                                                const float* __restrict__ dis,
                                                const float* __restrict__ xl,
                                                float* __restrict__ out, int N) {
    __shared__ int   sc[128];
    __shared__ float sn[128];
    const int i = blockIdx.x;
    const int t = threadIdx.x;
    const int beg = offs[i], end = offs[i + 1];
    const float di = dis[i];
    float acc = di * di * xl[i * D + t];
    for (int base = beg; base < end; base += 128) {
        int m = end - base; if (m > 128) m = 128;
        __syncthreads();
        if (t < m) {
            int c = ecol[base + t];
            sc[t] = c;
            sn[t] = di * dis[c];
        }
        __syncthreads();
        for (int j = 0; j < m; ++j)
            acc = fmaf(sn[j], xl[sc[j] * D + t], acc);
    }
    out[i * D + t] = acc;
}

// ======================= GEMM (unchanged) ================================

#define GEMM_R 8
__global__ __launch_bounds__(128) void k_gemm(const float* __restrict__ x,
                                              const float* __restrict__ W,
                                              const float* __restrict__ b,
                                              float* __restrict__ xl, int N) {
    __shared__ float xs[GEMM_R][D];
    const int c  = threadIdx.x;
    const int r0 = blockIdx.x * GEMM_R;
    #pragma unroll
    for (int r = 0; r < GEMM_R; ++r) {
        int row = r0 + r;
        xs[r][c] = (row < N) ? x[row * D + c] : 0.0f;
    }
    __syncthreads();

    float acc[GEMM_R];
    const float bc = b[c];
    #pragma unroll
    for (int r = 0; r < GEMM_R; ++r) acc[r] = bc;

    for (int k = 0; k < D; k += 4) {
        const float w0 = W[(k + 0) * D + c];
        const float w1 = W[(k + 1) * D + c];
        const float w2 = W[(k + 2) * D + c];
        const float w3 = W[(k + 3) * D + c];
        #pragma unroll
        for (int r = 0; r < GEMM_R; ++r) {
            const float4 xv = *reinterpret_cast<const float4*>(&xs[r][k]);
            acc[r] = fmaf(xv.x, w0, acc[r]);
            acc[r] = fmaf(xv.y, w1, acc[r]);
            acc[r] = fmaf(xv.z, w2, acc[r]);
            acc[r] = fmaf(xv.w, w3, acc[r]);
        }
    }
    #pragma unroll
    for (int r = 0; r < GEMM_R; ++r) {
        int row = r0 + r;
        if (row < N) xl[row * D + c] = acc[r];
    }
}

// ======================= fallback (R1 atomic path) =======================

__global__ __launch_bounds__(256) void k_self(const float* __restrict__ xl,
                                              const float* __restrict__ dis,
                                              float* __restrict__ out, int N) {
    int gid = blockIdx.x * 256 + threadIdx.x;
    int i = gid >> 7;
    if (i < N) {
        float d = dis[i];
        out[gid] = d * d * xl[gid];
    }
}

__global__ __launch_bounds__(256) void k_scatter(const int* __restrict__ rows,
                                                 const int* __restrict__ cols,
                                                 const float* __restrict__ dis,
                                                 const float* __restrict__ xl,
                                                 float* __restrict__ out, int E) {
    long long gid = (long long)blockIdx.x * 256 + threadIdx.x;
    int e    = (int)(gid >> 6);
    int lane = (int)(gid & 63);
    if (e >= E) return;
    const int row = rows[e];
    const int col = cols[e];
    const float nrm = dis[row] * dis[col];
    atomicAdd(&out[row * D + lane],      nrm * xl[col * D + lane]);
    atomicAdd(&out[row * D + 64 + lane], nrm * xl[col * D + 64 + lane]);
}

// ======================= launch ==========================================

extern "C" void kernel_launch(void* const* d_in, const int* in_sizes, int n_in,
                              void* d_out, int out_size, void* d_ws, size_t ws_size,
                              hipStream_t stream) {
    const float* x   = (const float*)d_in[0];
    const int*   ei  = (const int*)d_in[1];
    const float* W   = (const float*)d_in[2];
    const float* b   = (const float*)d_in[3];
    float*       out = (float*)d_out;

    const int N = in_sizes[0] / D;   // 50000
    const int E = in_sizes[1] / 2;   // 1.6M
    const int* rows = ei;
    const int* cols = ei + E;

    const int nb = (N + SCAN_B - 1) / SCAN_B;   // 196 scan blocks

    // ws layout (4B units)
    char* p = (char*)d_ws;
    size_t need = 0;
    float* xl     = (float*)(p + need); need += (size_t)N * D * 4;
    float* dis    = (float*)(p + need); need += (size_t)N * 4;
    int*   cntr   = (int*)  (p + need); need += (size_t)N * 4;
    int*   cntc   = (int*)  (p + need); need += (size_t)N * 4;
    int*   incl   = (int*)  (p + need); need += (size_t)N * 4;
    int*   offs   = (int*)  (p + need); need += (size_t)(N + 1) * 4;
    int*   cursor = (int*)  (p + need); need += (size_t)N * 4;
    int*   bsum   = (int*)  (p + need); need += (size_t)SCAN_B * 4;
    int*   ecol   = (int*)  (p + need); need += (size_t)E * 4;

    const int gN  = (N + 255) / 256;
    const int gE  = (E + 255) / 256;
    const int gND = ((N * D) + 255) / 256;

    if (ws_size >= need) {
        // --- CSR path ---
        k_zero <<<(2 * N + 255) / 256, 256, 0, stream>>>(cntr, 2 * N); // cntr+cntc adjacent
        k_hist <<<gE, 256, 0, stream>>>(rows, cols, cntr, cntc, E);
        k_dis  <<<gN, 256, 0, stream>>>(cntc, dis, N);
        k_scan1<<<nb, SCAN_B, 0, stream>>>(cntr, incl, bsum, N);
        k_scan2<<<1,  SCAN_B, 0, stream>>>(bsum, nb);
        k_scan3<<<nb, SCAN_B, 0, stream>>>(incl, cntr, bsum, offs, cursor, N, E);
        k_bin  <<<gE, 256, 0, stream>>>(rows, cols, cursor, ecol, E);
        k_gemm <<<(N + GEMM_R - 1) / GEMM_R, 128, 0, stream>>>(x, W, b, xl, N);
        k_reduce<<<N, 128, 0, stream>>>(offs, ecol, dis, xl, out, N);
    } else {
        // --- fallback: R1 atomic scatter path ---
        k_zero <<<gN, 256, 0, stream>>>(cntc, N);
        k_hist <<<gE, 256, 0, stream>>>(rows, cols, cntc, cntc, E); // only col counts matter
        k_dis  <<<gN, 256, 0, stream>>>(cntc, dis, N);
        k_gemm <<<(N + GEMM_R - 1) / GEMM_R, 128, 0, stream>>>(x, W, b, xl, N);
        k_self <<<gND, 256, 0, stream>>>(xl, dis, out, N);
        long long st = (long long)E * 64;
        k_scatter<<<(int)((st + 255) / 256), 256, 0, stream>>>(rows, cols, dis, xl, out, E);
    }
}